// Round 6
// baseline (296.171 us; speedup 1.0000x reference)
//
#include <hip/hip_runtime.h>
#include <math.h>

// Round 6: 2 blocks/CU conv for inter-block barrier overlap.
//   tsep_k : 256 blocks x 1024 thr, 1 pair each, single 69.6KB buffer (full GPU).
//   fftconv6: 512 blocks x 512 thr, single 69.6KB buffer -> 2 blocks/CU.
//     Each block owns 2 pairs (4 channels, float4 I/O) processed sequentially;
//     pair1 input / pair0 output ride in regs across the other pair's FFTs.
//     Each thread: 2 butterflies/stage (p=tid, p+512) sharing one sincos+chain
//     (512 % q == 0 for all LDS stages q=128,16,2).
// FFT: register radix-8, 8192 = 8^4*2; slot perm = octal digit reversal.

#define NFFT 8192
#define TTHR 1024
#define CTHR 512
#define PAD(i) ((i) + ((i) >> 4))
#define LDS_ELEMS (NFFT + (NFFT >> 4))          // 8704 float2 = 69632 B
#define TWO_PI 6.28318530717958647692f
#define RSQRT2 0.70710678118654752440f

__device__ __forceinline__ float2 cadd(float2 a, float2 b){ return make_float2(a.x+b.x, a.y+b.y); }
__device__ __forceinline__ float2 csub(float2 a, float2 b){ return make_float2(a.x-b.x, a.y-b.y); }
__device__ __forceinline__ float2 cmul(float2 a, float2 b){ return make_float2(a.x*b.x - a.y*b.y, a.x*b.y + a.y*b.x); }
__device__ __forceinline__ float2 mulnegi(float2 a){ return make_float2(a.y, -a.x); }
__device__ __forceinline__ float2 mulposi(float2 a){ return make_float2(-a.y, a.x); }
__device__ __forceinline__ float2 mulw81(float2 z){ return make_float2(RSQRT2*(z.x+z.y), RSQRT2*(z.y-z.x)); }  // e^{-i pi/4}
__device__ __forceinline__ float2 mulw83(float2 z){ return make_float2(RSQRT2*(z.y-z.x), -RSQRT2*(z.x+z.y)); } // e^{-i 3pi/4}
__device__ __forceinline__ float2 mulv81(float2 z){ return make_float2(RSQRT2*(z.x-z.y), RSQRT2*(z.x+z.y)); }  // e^{+i pi/4}
__device__ __forceinline__ float2 mulv83(float2 z){ return make_float2(-RSQRT2*(z.x+z.y), RSQRT2*(z.x-z.y)); } // e^{+i 3pi/4}

__device__ __forceinline__ int rev8_12(int u) {
    return ((u & 7) << 9) | (((u >> 3) & 7) << 6) | (((u >> 6) & 7) << 3) | ((u >> 9) & 7);
}

__device__ __forceinline__ void dft8_fwd(float2& a0, float2& a1, float2& a2, float2& a3,
                                         float2& a4, float2& a5, float2& a6, float2& a7) {
    float2 s02 = cadd(a0,a4), d02 = csub(a0,a4), s13 = cadd(a2,a6), d13 = csub(a2,a6);
    float2 E0 = cadd(s02,s13), E2 = csub(s02,s13);
    float2 E1 = cadd(d02, mulnegi(d13)), E3 = csub(d02, mulnegi(d13));
    float2 t02 = cadd(a1,a5), u02 = csub(a1,a5), t13 = cadd(a3,a7), u13 = csub(a3,a7);
    float2 O0 = cadd(t02,t13), O2 = csub(t02,t13);
    float2 O1 = cadd(u02, mulnegi(u13)), O3 = csub(u02, mulnegi(u13));
    float2 W1 = mulw81(O1), W2 = mulnegi(O2), W3 = mulw83(O3);
    a0 = cadd(E0,O0); a4 = csub(E0,O0);
    a1 = cadd(E1,W1); a5 = csub(E1,W1);
    a2 = cadd(E2,W2); a6 = csub(E2,W2);
    a3 = cadd(E3,W3); a7 = csub(E3,W3);
}

__device__ __forceinline__ void dft8_inv(float2& a0, float2& a1, float2& a2, float2& a3,
                                         float2& a4, float2& a5, float2& a6, float2& a7) {
    float2 s02 = cadd(a0,a4), d02 = csub(a0,a4), s13 = cadd(a2,a6), d13 = csub(a2,a6);
    float2 P0 = cadd(s02,s13), P2 = csub(s02,s13);
    float2 P1 = cadd(d02, mulposi(d13)), P3 = csub(d02, mulposi(d13));
    float2 t02 = cadd(a1,a5), u02 = csub(a1,a5), t13 = cadd(a3,a7), u13 = csub(a3,a7);
    float2 Q0 = cadd(t02,t13), Q2 = csub(t02,t13);
    float2 Q1 = cadd(u02, mulposi(u13)), Q3 = csub(u02, mulposi(u13));
    float2 W1 = mulv81(Q1), W2 = mulposi(Q2), W3 = mulv83(Q3);
    a0 = cadd(P0,Q0); a4 = csub(P0,Q0);
    a1 = cadd(P1,W1); a5 = csub(P1,W1);
    a2 = cadd(P2,W2); a6 = csub(P2,W2);
    a3 = cadd(P3,W3); a7 = csub(P3,W3);
}

__device__ __forceinline__ void fwd_one(float2* __restrict__ S, int B, int q,
    float2 w1,float2 w2,float2 w3,float2 w4,float2 w5,float2 w6,float2 w7) {
    const int i0=PAD(B),i1=PAD(B+q),i2=PAD(B+2*q),i3=PAD(B+3*q),
              i4=PAD(B+4*q),i5=PAD(B+5*q),i6=PAD(B+6*q),i7=PAD(B+7*q);
    float2 a0=S[i0],a1=S[i1],a2=S[i2],a3=S[i3],a4=S[i4],a5=S[i5],a6=S[i6],a7=S[i7];
    dft8_fwd(a0,a1,a2,a3,a4,a5,a6,a7);
    S[i0]=a0;           S[i1]=cmul(a1,w1); S[i2]=cmul(a2,w2); S[i3]=cmul(a3,w3);
    S[i4]=cmul(a4,w4);  S[i5]=cmul(a5,w5); S[i6]=cmul(a6,w6); S[i7]=cmul(a7,w7);
}

__device__ __forceinline__ void inv_one(float2* __restrict__ S, int B, int q,
    float2 w1,float2 w2,float2 w3,float2 w4,float2 w5,float2 w6,float2 w7) {
    const int i0=PAD(B),i1=PAD(B+q),i2=PAD(B+2*q),i3=PAD(B+3*q),
              i4=PAD(B+4*q),i5=PAD(B+5*q),i6=PAD(B+6*q),i7=PAD(B+7*q);
    float2 a0=S[i0];
    float2 a1=cmul(S[i1],w1), a2=cmul(S[i2],w2), a3=cmul(S[i3],w3), a4=cmul(S[i4],w4),
           a5=cmul(S[i5],w5), a6=cmul(S[i6],w6), a7=cmul(S[i7],w7);
    dft8_inv(a0,a1,a2,a3,a4,a5,a6,a7);
    S[i0]=a0; S[i1]=a1; S[i2]=a2; S[i3]=a3; S[i4]=a4; S[i5]=a5; S[i6]=a6; S[i7]=a7;
}

#define WCHAIN(w1, w2,w3,w4,w5,w6,w7) \
    float2 w2 = cmul(w1,w1), w3 = cmul(w2,w1), w4 = cmul(w2,w2), \
           w5 = cmul(w4,w1), w6 = cmul(w4,w2), w7 = cmul(w4,w3)

// ---------------- dual-butterfly LDS stages (conv, 512 threads) ----------------
template<int LQ>
__device__ __forceinline__ void fwd_stage_dual(float2* __restrict__ S, int tid) {
    const int q = 1 << LQ;
    const int m = tid & (q - 1);
    const int B1 = ((tid >> LQ) << (LQ + 3)) + m;
    const int B2 = (((tid + CTHR) >> LQ) << (LQ + 3)) + m;  // 512 % q == 0
    float sn, cs;
    __sincosf(-TWO_PI * (float)m / (float)(q << 3), &sn, &cs);
    float2 w1 = make_float2(cs, sn);
    WCHAIN(w1, w2,w3,w4,w5,w6,w7);
    fwd_one(S, B1, q, w1,w2,w3,w4,w5,w6,w7);
    fwd_one(S, B2, q, w1,w2,w3,w4,w5,w6,w7);
}

template<int LQ>
__device__ __forceinline__ void inv_stage_dual(float2* __restrict__ S, int tid) {
    const int q = 1 << LQ;
    const int m = tid & (q - 1);
    const int B1 = ((tid >> LQ) << (LQ + 3)) + m;
    const int B2 = (((tid + CTHR) >> LQ) << (LQ + 3)) + m;
    float sn, cs;
    __sincosf(TWO_PI * (float)m / (float)(q << 3), &sn, &cs);
    float2 w1 = make_float2(cs, sn);
    WCHAIN(w1, w2,w3,w4,w5,w6,w7);
    inv_one(S, B1, q, w1,w2,w3,w4,w5,w6,w7);
    inv_one(S, B2, q, w1,w2,w3,w4,w5,w6,w7);
}

// ---------------- single-butterfly LDS stages (tsep, 1024 threads) -------------
template<int LQ>
__device__ __forceinline__ void fwd_stage_1b(float2* __restrict__ S, int tid) {
    const int q = 1 << LQ;
    const int m = tid & (q - 1);
    const int B = ((tid >> LQ) << (LQ + 3)) + m;
    float sn, cs;
    __sincosf(-TWO_PI * (float)m / (float)(q << 3), &sn, &cs);
    float2 w1 = make_float2(cs, sn);
    WCHAIN(w1, w2,w3,w4,w5,w6,w7);
    fwd_one(S, B, q, w1,w2,w3,w4,w5,w6,w7);
}

// x stage 1 (L=8192, inputs 4..7 zero), butterfly index p, write with twiddles
__device__ __forceinline__ void xstage1(float2 a0, float2 a1, float2 a2, float2 a3,
    float2* __restrict__ S, int p,
    float2 w1,float2 w2,float2 w3,float2 w4,float2 w5,float2 w6,float2 w7) {
    float2 s02 = cadd(a0,a2), d02 = csub(a0,a2), s13 = cadd(a1,a3), d13 = csub(a1,a3);
    float2 F0 = cadd(s02,s13), F2 = csub(s02,s13);
    float2 F1 = cadd(d02, mulnegi(d13)), F3 = csub(d02, mulnegi(d13));
    float2 g1 = mulw81(a1), g2 = mulnegi(a2), g3 = mulw83(a3);
    float2 gs02 = cadd(a0,g2), gd02 = csub(a0,g2), gs13 = cadd(g1,g3), gd13 = csub(g1,g3);
    float2 G0 = cadd(gs02,gs13), G2 = csub(gs02,gs13);
    float2 G1 = cadd(gd02, mulnegi(gd13)), G3 = csub(gd02, mulnegi(gd13));
    S[PAD(p)]        = F0;
    S[PAD(p + 1024)] = cmul(G0, w1);
    S[PAD(p + 2048)] = cmul(F1, w2);
    S[PAD(p + 3072)] = cmul(G1, w3);
    S[PAD(p + 4096)] = cmul(F2, w4);
    S[PAD(p + 5120)] = cmul(G2, w5);
    S[PAD(p + 6144)] = cmul(F3, w6);
    S[PAD(p + 7168)] = cmul(G3, w7);
}

// t stage 1 (full 8 inputs), butterfly index p
__device__ __forceinline__ void tstage1(float2 a0, float2 a1, float2 a2, float2 a3,
    float2 a4, float2 a5, float2 a6, float2 a7, float2* __restrict__ S, int p,
    float2 w1,float2 w2,float2 w3,float2 w4,float2 w5,float2 w6,float2 w7) {
    dft8_fwd(a0,a1,a2,a3,a4,a5,a6,a7);
    S[PAD(p)]        = a0;
    S[PAD(p + 1024)] = cmul(a1, w1);
    S[PAD(p + 2048)] = cmul(a2, w2);
    S[PAD(p + 3072)] = cmul(a3, w3);
    S[PAD(p + 4096)] = cmul(a4, w4);
    S[PAD(p + 5120)] = cmul(a5, w5);
    S[PAD(p + 6144)] = cmul(a6, w6);
    S[PAD(p + 7168)] = cmul(a7, w7);
}

// final inverse stage (L=8192): only time outputs j=0..3 of butterfly p
__device__ __forceinline__ void inv_final(const float2* __restrict__ S, int p,
    float2 w1,float2 w2,float2 w3,float2 w4,float2 w5,float2 w6,float2 w7,
    float2& r0, float2& r1, float2& r2, float2& r3) {
    float2 z0 = S[PAD(p)];
    float2 z1 = cmul(S[PAD(p + 1024)], w1);
    float2 z2 = cmul(S[PAD(p + 2048)], w2);
    float2 z3 = cmul(S[PAD(p + 3072)], w3);
    float2 z4 = cmul(S[PAD(p + 4096)], w4);
    float2 z5 = cmul(S[PAD(p + 5120)], w5);
    float2 z6 = cmul(S[PAD(p + 6144)], w6);
    float2 z7 = cmul(S[PAD(p + 7168)], w7);
    float2 s02 = cadd(z0,z4), d02 = csub(z0,z4), s13 = cadd(z2,z6), d13 = csub(z2,z6);
    float2 P0 = cadd(s02,s13), P2 = csub(s02,s13);
    float2 P1 = cadd(d02, mulposi(d13)), P3 = csub(d02, mulposi(d13));
    float2 t02 = cadd(z1,z5), u02 = csub(z1,z5), t13 = cadd(z3,z7), u13 = csub(z3,z7);
    float2 Q0 = cadd(t02,t13), Q2 = csub(t02,t13);
    float2 Q1 = cadd(u02, mulposi(u13)), Q3 = csub(u02, mulposi(u13));
    r0 = cadd(P0, Q0);
    r1 = cadd(P1, mulv81(Q1));
    r2 = cadd(P2, mulposi(Q2));
    r3 = cadd(P3, mulv83(Q3));
}

// fwd-r2 + conj-symmetry sep + Tsep mul + inv-r2 (regs across one barrier), 512 thr
__device__ __forceinline__ void sep_conv(float2* __restrict__ S,
                                         const float4* __restrict__ tb, int tid) {
    float2 Wr[16];
    #pragma unroll
    for (int it = 0; it < 8; ++it) {
        int u = tid + (it << 9);
        int K = rev8_12(u);
        int v = rev8_12((4096 - K) & 4095);
        float2 V0 = S[PAD(2*u)], V1 = S[PAD(2*u + 1)];
        float2 Za = cadd(V0, V1), Zb = csub(V0, V1);
        float2 Zc, Zd;
        if (u == 0) { Zc = Zb; Zd = Za; }
        else {
            float2 U0 = S[PAD(2*v)], U1 = S[PAD(2*v + 1)];
            Zc = cadd(U0, U1); Zd = csub(U0, U1);
        }
        float4 t0 = tb[2*u], t1 = tb[2*u + 1];
        float2 Xd = make_float2((Za.x + Zd.x) * 0.5f, (Za.y - Zd.y) * 0.5f);
        float2 Xe = make_float2((Za.y + Zd.y) * 0.5f, (Zd.x - Za.x) * 0.5f);
        float2 A0 = cmul(Xd, make_float2(t0.x, t0.y));
        float2 B0 = cmul(Xe, make_float2(t0.z, t0.w));
        float2 Q0 = make_float2(A0.x - B0.y, A0.y + B0.x);
        float2 Yd = make_float2((Zb.x + Zc.x) * 0.5f, (Zb.y - Zc.y) * 0.5f);
        float2 Ye = make_float2((Zb.y + Zc.y) * 0.5f, (Zc.x - Zb.x) * 0.5f);
        float2 A1 = cmul(Yd, make_float2(t1.x, t1.y));
        float2 B1 = cmul(Ye, make_float2(t1.z, t1.w));
        float2 Q1 = make_float2(A1.x - B1.y, A1.y + B1.x);
        Wr[2*it]     = cadd(Q0, Q1);
        Wr[2*it + 1] = csub(Q0, Q1);
    }
    __syncthreads();
    #pragma unroll
    for (int it = 0; it < 8; ++it) {
        int u = tid + (it << 9);
        S[PAD(2*u)]     = Wr[2*it];
        S[PAD(2*u + 1)] = Wr[2*it + 1];
    }
    __syncthreads();
}

// ---------------- T precompute: 256 blocks x 1024 thr, 1 pair each -------------
__global__ __launch_bounds__(TTHR, 4) void tsep_k(
    const float* __restrict__ T, float4* __restrict__ Tsep)
{
    extern __shared__ float2 S[];
    const int tid = threadIdx.x;
    const int c = blockIdx.x;              // pair [0,256)
    const float* tp = T + (c << 1);

    {
        float2 a0 = *(const float2*)(tp + (size_t)(tid       ) * 512);
        float2 a1 = *(const float2*)(tp + (size_t)(tid + 1024) * 512);
        float2 a2 = *(const float2*)(tp + (size_t)(tid + 2048) * 512);
        float2 a3 = *(const float2*)(tp + (size_t)(tid + 3072) * 512);
        float2 a4 = *(const float2*)(tp + (size_t)(tid + 4096) * 512);
        float2 a5 = *(const float2*)(tp + (size_t)(tid + 5120) * 512);
        float2 a6 = *(const float2*)(tp + (size_t)(tid + 6144) * 512);
        float2 a7 = *(const float2*)(tp + (size_t)(tid + 7168) * 512);
        float sn, cs;
        __sincosf(-TWO_PI * (float)tid / 8192.0f, &sn, &cs);
        float2 w1 = make_float2(cs, sn);
        WCHAIN(w1, w2,w3,w4,w5,w6,w7);
        tstage1(a0,a1,a2,a3,a4,a5,a6,a7, S, tid, w1,w2,w3,w4,w5,w6,w7);
    }
    __syncthreads();
    fwd_stage_1b<7>(S, tid); __syncthreads();
    fwd_stage_1b<4>(S, tid); __syncthreads();
    fwd_stage_1b<1>(S, tid); __syncthreads();

    const float sc = 0.5f / (float)NFFT;
    float4* tb = Tsep + (size_t)c * NFFT;
    #pragma unroll
    for (int it = 0; it < 4; ++it) {
        int u = tid + (it << 10);
        int K = rev8_12(u);
        int v = rev8_12((4096 - K) & 4095);
        float2 V0 = S[PAD(2*u)], V1 = S[PAD(2*u + 1)];
        float2 Za = cadd(V0, V1), Zb = csub(V0, V1);
        float2 Zc, Zd;
        if (u == 0) { Zc = Zb; Zd = Za; }
        else {
            float2 U0 = S[PAD(2*v)], U1 = S[PAD(2*v + 1)];
            Zc = cadd(U0, U1); Zd = csub(U0, U1);
        }
        tb[2*u]     = make_float4((Za.x + Zd.x) * sc, (Za.y - Zd.y) * sc,
                                  (Za.y + Zd.y) * sc, (Zd.x - Za.x) * sc);
        tb[2*u + 1] = make_float4((Zb.x + Zc.x) * sc, (Zb.y - Zc.y) * sc,
                                  (Zb.y + Zc.y) * sc, (Zc.x - Zb.x) * sc);
    }
}

// ---------------- main conv: 512 blocks x 512 thr, 2 blocks/CU ------------------
__global__ __launch_bounds__(CTHR, 4) void fftconv6(
    const float* __restrict__ X, const float4* __restrict__ Tsep,
    float* __restrict__ O)
{
    extern __shared__ float2 S[];
    const int tid = threadIdx.x;

    // h -> (xcd, pgo, b): XCD x owns pair-groups [16x,16x+16) for all b
    int h = blockIdx.x;                    // [0,512)
    int xcd = h & 7;
    int r = h >> 3;                        // [0,64)
    int pgo = r & 15;
    int b = r >> 4;                        // [0,4)
    int g2 = (xcd << 4) + pgo;             // pair-group [0,128), 2 pairs = 4 channels
    const int dbase = g2 << 2;

    // ---- load all 8 rows as float4 (pair0 = .xy, pair1 = .zw) ----
    const float* xp = X + (size_t)b * 4096 * 512 + dbase;
    float4 l[8];
    #pragma unroll
    for (int j = 0; j < 8; ++j)
        l[j] = *(const float4*)(xp + (size_t)(tid + j * 512) * 512);

    const float2 C512F = make_float2(0.92387953251128675613f, -0.38268343236508977173f); // e^{-i pi/8}
    const float2 C512I = make_float2(0.92387953251128675613f,  0.38268343236508977173f); // e^{+i pi/8}

    float2 out0[8];

    // ================= pair 0 (.xy) =================
    {
        float sn, cs;
        __sincosf(-TWO_PI * (float)tid / 8192.0f, &sn, &cs);
        float2 w1 = make_float2(cs, sn);
        WCHAIN(w1, w2,w3,w4,w5,w6,w7);
        xstage1(make_float2(l[0].x,l[0].y), make_float2(l[2].x,l[2].y),
                make_float2(l[4].x,l[4].y), make_float2(l[6].x,l[6].y),
                S, tid, w1,w2,w3,w4,w5,w6,w7);
        float2 v1 = cmul(w1, C512F);
        WCHAIN(v1, v2,v3,v4,v5,v6,v7);
        xstage1(make_float2(l[1].x,l[1].y), make_float2(l[3].x,l[3].y),
                make_float2(l[5].x,l[5].y), make_float2(l[7].x,l[7].y),
                S, tid + 512, v1,v2,v3,v4,v5,v6,v7);
    }
    __syncthreads();
    fwd_stage_dual<7>(S, tid); __syncthreads();
    fwd_stage_dual<4>(S, tid); __syncthreads();
    fwd_stage_dual<1>(S, tid); __syncthreads();
    sep_conv(S, Tsep + (size_t)(2*g2) * NFFT, tid);
    inv_stage_dual<1>(S, tid); __syncthreads();
    inv_stage_dual<4>(S, tid); __syncthreads();
    inv_stage_dual<7>(S, tid); __syncthreads();
    {
        float sn, cs;
        __sincosf(TWO_PI * (float)tid / 8192.0f, &sn, &cs);
        float2 w1 = make_float2(cs, sn);
        WCHAIN(w1, w2,w3,w4,w5,w6,w7);
        inv_final(S, tid, w1,w2,w3,w4,w5,w6,w7, out0[0], out0[2], out0[4], out0[6]);
        float2 v1 = cmul(w1, C512I);
        WCHAIN(v1, v2,v3,v4,v5,v6,v7);
        inv_final(S, tid + 512, v1,v2,v3,v4,v5,v6,v7, out0[1], out0[3], out0[5], out0[7]);
    }
    __syncthreads();   // all reads of S done before pair1 overwrites

    // ================= pair 1 (.zw) =================
    float2 out1[8];
    {
        float sn, cs;
        __sincosf(-TWO_PI * (float)tid / 8192.0f, &sn, &cs);
        float2 w1 = make_float2(cs, sn);
        WCHAIN(w1, w2,w3,w4,w5,w6,w7);
        xstage1(make_float2(l[0].z,l[0].w), make_float2(l[2].z,l[2].w),
                make_float2(l[4].z,l[4].w), make_float2(l[6].z,l[6].w),
                S, tid, w1,w2,w3,w4,w5,w6,w7);
        float2 v1 = cmul(w1, C512F);
        WCHAIN(v1, v2,v3,v4,v5,v6,v7);
        xstage1(make_float2(l[1].z,l[1].w), make_float2(l[3].z,l[3].w),
                make_float2(l[5].z,l[5].w), make_float2(l[7].z,l[7].w),
                S, tid + 512, v1,v2,v3,v4,v5,v6,v7);
    }
    __syncthreads();
    fwd_stage_dual<7>(S, tid); __syncthreads();
    fwd_stage_dual<4>(S, tid); __syncthreads();
    fwd_stage_dual<1>(S, tid); __syncthreads();
    sep_conv(S, Tsep + (size_t)(2*g2 + 1) * NFFT, tid);
    inv_stage_dual<1>(S, tid); __syncthreads();
    inv_stage_dual<4>(S, tid); __syncthreads();
    inv_stage_dual<7>(S, tid); __syncthreads();
    {
        float sn, cs;
        __sincosf(TWO_PI * (float)tid / 8192.0f, &sn, &cs);
        float2 w1 = make_float2(cs, sn);
        WCHAIN(w1, w2,w3,w4,w5,w6,w7);
        inv_final(S, tid, w1,w2,w3,w4,w5,w6,w7, out1[0], out1[2], out1[4], out1[6]);
        float2 v1 = cmul(w1, C512I);
        WCHAIN(v1, v2,v3,v4,v5,v6,v7);
        inv_final(S, tid + 512, v1,v2,v3,v4,v5,v6,v7, out1[1], out1[3], out1[5], out1[7]);
    }

    // ---- store float4 (4 channels) ----
    float* op = O + (size_t)b * 4096 * 512 + dbase;
    #pragma unroll
    for (int j = 0; j < 8; ++j)
        *(float4*)(op + (size_t)(tid + j * 512) * 512) =
            make_float4(out0[j].x, out0[j].y, out1[j].x, out1[j].y);
}

extern "C" void kernel_launch(void* const* d_in, const int* in_sizes, int n_in,
                              void* d_out, int out_size, void* d_ws, size_t ws_size,
                              hipStream_t stream)
{
    const float* x = (const float*)d_in[0];   // (4, 4096, 512)
    const float* t = (const float*)d_in[1];   // (8192, 512)
    float* out = (float*)d_out;               // (4, 4096, 512)
    float4* tsep = (float4*)d_ws;             // 256*8192*16 B = 32 MB

    const int lds = (int)(LDS_ELEMS * sizeof(float2));   // 69632
    (void)hipFuncSetAttribute((const void*)tsep_k,
                              hipFuncAttributeMaxDynamicSharedMemorySize, lds);
    (void)hipFuncSetAttribute((const void*)fftconv6,
                              hipFuncAttributeMaxDynamicSharedMemorySize, lds);

    tsep_k<<<256, TTHR, lds, stream>>>(t, tsep);
    fftconv6<<<512, CTHR, lds, stream>>>(x, tsep, out);
}

// Round 7
// 112.268 us; speedup vs baseline: 2.6381x; 2.6381x over previous
//
#include <hip/hip_runtime.h>
#include <math.h>

// Round 7: 2 blocks/CU without register riding (round-6 spilled: WRITE 495MB).
//   tsep_k : 256 blocks x 1024 thr, 1 pair each, single 69.6KB buffer, 2 blk/CU.
//   fftconv7: 1024 blocks x 512 thr, ONE pair per block, single 69.6KB buffer
//     -> 2 blocks/CU, 16 waves. Dual butterfly per thread (p=tid, tid+512),
//     float2 global I/O consumed/produced immediately (no state across barriers).
//   XCD swizzle lbid=64k+8x+w: 8 blocks sharing each 64B output line AND the
//   4 b-variants sharing each Tsep panel land on one XCD.
// FFT: register radix-8, 8192 = 8^4*2; slot perm = octal digit reversal.

#define NFFT 8192
#define TTHR 1024
#define CTHR 512
#define PAD(i) ((i) + ((i) >> 4))
#define LDS_ELEMS (NFFT + (NFFT >> 4))          // 8704 float2 = 69632 B
#define TWO_PI 6.28318530717958647692f
#define RSQRT2 0.70710678118654752440f

__device__ __forceinline__ float2 cadd(float2 a, float2 b){ return make_float2(a.x+b.x, a.y+b.y); }
__device__ __forceinline__ float2 csub(float2 a, float2 b){ return make_float2(a.x-b.x, a.y-b.y); }
__device__ __forceinline__ float2 cmul(float2 a, float2 b){ return make_float2(a.x*b.x - a.y*b.y, a.x*b.y + a.y*b.x); }
__device__ __forceinline__ float2 mulnegi(float2 a){ return make_float2(a.y, -a.x); }
__device__ __forceinline__ float2 mulposi(float2 a){ return make_float2(-a.y, a.x); }
__device__ __forceinline__ float2 mulw81(float2 z){ return make_float2(RSQRT2*(z.x+z.y), RSQRT2*(z.y-z.x)); }  // e^{-i pi/4}
__device__ __forceinline__ float2 mulw83(float2 z){ return make_float2(RSQRT2*(z.y-z.x), -RSQRT2*(z.x+z.y)); } // e^{-i 3pi/4}
__device__ __forceinline__ float2 mulv81(float2 z){ return make_float2(RSQRT2*(z.x-z.y), RSQRT2*(z.x+z.y)); }  // e^{+i pi/4}
__device__ __forceinline__ float2 mulv83(float2 z){ return make_float2(-RSQRT2*(z.x+z.y), RSQRT2*(z.x-z.y)); } // e^{+i 3pi/4}

__device__ __forceinline__ int rev8_12(int u) {
    return ((u & 7) << 9) | (((u >> 3) & 7) << 6) | (((u >> 6) & 7) << 3) | ((u >> 9) & 7);
}

__device__ __forceinline__ void dft8_fwd(float2& a0, float2& a1, float2& a2, float2& a3,
                                         float2& a4, float2& a5, float2& a6, float2& a7) {
    float2 s02 = cadd(a0,a4), d02 = csub(a0,a4), s13 = cadd(a2,a6), d13 = csub(a2,a6);
    float2 E0 = cadd(s02,s13), E2 = csub(s02,s13);
    float2 E1 = cadd(d02, mulnegi(d13)), E3 = csub(d02, mulnegi(d13));
    float2 t02 = cadd(a1,a5), u02 = csub(a1,a5), t13 = cadd(a3,a7), u13 = csub(a3,a7);
    float2 O0 = cadd(t02,t13), O2 = csub(t02,t13);
    float2 O1 = cadd(u02, mulnegi(u13)), O3 = csub(u02, mulnegi(u13));
    float2 W1 = mulw81(O1), W2 = mulnegi(O2), W3 = mulw83(O3);
    a0 = cadd(E0,O0); a4 = csub(E0,O0);
    a1 = cadd(E1,W1); a5 = csub(E1,W1);
    a2 = cadd(E2,W2); a6 = csub(E2,W2);
    a3 = cadd(E3,W3); a7 = csub(E3,W3);
}

__device__ __forceinline__ void dft8_inv(float2& a0, float2& a1, float2& a2, float2& a3,
                                         float2& a4, float2& a5, float2& a6, float2& a7) {
    float2 s02 = cadd(a0,a4), d02 = csub(a0,a4), s13 = cadd(a2,a6), d13 = csub(a2,a6);
    float2 P0 = cadd(s02,s13), P2 = csub(s02,s13);
    float2 P1 = cadd(d02, mulposi(d13)), P3 = csub(d02, mulposi(d13));
    float2 t02 = cadd(a1,a5), u02 = csub(a1,a5), t13 = cadd(a3,a7), u13 = csub(a3,a7);
    float2 Q0 = cadd(t02,t13), Q2 = csub(t02,t13);
    float2 Q1 = cadd(u02, mulposi(u13)), Q3 = csub(u02, mulposi(u13));
    float2 W1 = mulv81(Q1), W2 = mulposi(Q2), W3 = mulv83(Q3);
    a0 = cadd(P0,Q0); a4 = csub(P0,Q0);
    a1 = cadd(P1,W1); a5 = csub(P1,W1);
    a2 = cadd(P2,W2); a6 = csub(P2,W2);
    a3 = cadd(P3,W3); a7 = csub(P3,W3);
}

__device__ __forceinline__ void fwd_one(float2* __restrict__ S, int B, int q,
    float2 w1,float2 w2,float2 w3,float2 w4,float2 w5,float2 w6,float2 w7) {
    const int i0=PAD(B),i1=PAD(B+q),i2=PAD(B+2*q),i3=PAD(B+3*q),
              i4=PAD(B+4*q),i5=PAD(B+5*q),i6=PAD(B+6*q),i7=PAD(B+7*q);
    float2 a0=S[i0],a1=S[i1],a2=S[i2],a3=S[i3],a4=S[i4],a5=S[i5],a6=S[i6],a7=S[i7];
    dft8_fwd(a0,a1,a2,a3,a4,a5,a6,a7);
    S[i0]=a0;           S[i1]=cmul(a1,w1); S[i2]=cmul(a2,w2); S[i3]=cmul(a3,w3);
    S[i4]=cmul(a4,w4);  S[i5]=cmul(a5,w5); S[i6]=cmul(a6,w6); S[i7]=cmul(a7,w7);
}

__device__ __forceinline__ void inv_one(float2* __restrict__ S, int B, int q,
    float2 w1,float2 w2,float2 w3,float2 w4,float2 w5,float2 w6,float2 w7) {
    const int i0=PAD(B),i1=PAD(B+q),i2=PAD(B+2*q),i3=PAD(B+3*q),
              i4=PAD(B+4*q),i5=PAD(B+5*q),i6=PAD(B+6*q),i7=PAD(B+7*q);
    float2 a0=S[i0];
    float2 a1=cmul(S[i1],w1), a2=cmul(S[i2],w2), a3=cmul(S[i3],w3), a4=cmul(S[i4],w4),
           a5=cmul(S[i5],w5), a6=cmul(S[i6],w6), a7=cmul(S[i7],w7);
    dft8_inv(a0,a1,a2,a3,a4,a5,a6,a7);
    S[i0]=a0; S[i1]=a1; S[i2]=a2; S[i3]=a3; S[i4]=a4; S[i5]=a5; S[i6]=a6; S[i7]=a7;
}

#define WCHAIN(w1, w2,w3,w4,w5,w6,w7) \
    float2 w2 = cmul(w1,w1), w3 = cmul(w2,w1), w4 = cmul(w2,w2), \
           w5 = cmul(w4,w1), w6 = cmul(w4,w2), w7 = cmul(w4,w3)

// dual-butterfly LDS stages (512 threads, p = tid and tid+512; 512 % q == 0)
template<int LQ>
__device__ __forceinline__ void fwd_stage_dual(float2* __restrict__ S, int tid) {
    const int q = 1 << LQ;
    const int m = tid & (q - 1);
    const int B1 = ((tid >> LQ) << (LQ + 3)) + m;
    const int B2 = (((tid + CTHR) >> LQ) << (LQ + 3)) + m;
    float sn, cs;
    __sincosf(-TWO_PI * (float)m / (float)(q << 3), &sn, &cs);
    float2 w1 = make_float2(cs, sn);
    WCHAIN(w1, w2,w3,w4,w5,w6,w7);
    fwd_one(S, B1, q, w1,w2,w3,w4,w5,w6,w7);
    fwd_one(S, B2, q, w1,w2,w3,w4,w5,w6,w7);
}

template<int LQ>
__device__ __forceinline__ void inv_stage_dual(float2* __restrict__ S, int tid) {
    const int q = 1 << LQ;
    const int m = tid & (q - 1);
    const int B1 = ((tid >> LQ) << (LQ + 3)) + m;
    const int B2 = (((tid + CTHR) >> LQ) << (LQ + 3)) + m;
    float sn, cs;
    __sincosf(TWO_PI * (float)m / (float)(q << 3), &sn, &cs);
    float2 w1 = make_float2(cs, sn);
    WCHAIN(w1, w2,w3,w4,w5,w6,w7);
    inv_one(S, B1, q, w1,w2,w3,w4,w5,w6,w7);
    inv_one(S, B2, q, w1,w2,w3,w4,w5,w6,w7);
}

// single-butterfly stage (tsep, 1024 threads)
template<int LQ>
__device__ __forceinline__ void fwd_stage_1b(float2* __restrict__ S, int tid) {
    const int q = 1 << LQ;
    const int m = tid & (q - 1);
    const int B = ((tid >> LQ) << (LQ + 3)) + m;
    float sn, cs;
    __sincosf(-TWO_PI * (float)m / (float)(q << 3), &sn, &cs);
    float2 w1 = make_float2(cs, sn);
    WCHAIN(w1, w2,w3,w4,w5,w6,w7);
    fwd_one(S, B, q, w1,w2,w3,w4,w5,w6,w7);
}

// x stage 1 (L=8192, inputs 4..7 zero), butterfly index p
__device__ __forceinline__ void xstage1(float2 a0, float2 a1, float2 a2, float2 a3,
    float2* __restrict__ S, int p,
    float2 w1,float2 w2,float2 w3,float2 w4,float2 w5,float2 w6,float2 w7) {
    float2 s02 = cadd(a0,a2), d02 = csub(a0,a2), s13 = cadd(a1,a3), d13 = csub(a1,a3);
    float2 F0 = cadd(s02,s13), F2 = csub(s02,s13);
    float2 F1 = cadd(d02, mulnegi(d13)), F3 = csub(d02, mulnegi(d13));
    float2 g1 = mulw81(a1), g2 = mulnegi(a2), g3 = mulw83(a3);
    float2 gs02 = cadd(a0,g2), gd02 = csub(a0,g2), gs13 = cadd(g1,g3), gd13 = csub(g1,g3);
    float2 G0 = cadd(gs02,gs13), G2 = csub(gs02,gs13);
    float2 G1 = cadd(gd02, mulnegi(gd13)), G3 = csub(gd02, mulnegi(gd13));
    S[PAD(p)]        = F0;
    S[PAD(p + 1024)] = cmul(G0, w1);
    S[PAD(p + 2048)] = cmul(F1, w2);
    S[PAD(p + 3072)] = cmul(G1, w3);
    S[PAD(p + 4096)] = cmul(F2, w4);
    S[PAD(p + 5120)] = cmul(G2, w5);
    S[PAD(p + 6144)] = cmul(F3, w6);
    S[PAD(p + 7168)] = cmul(G3, w7);
}

// t stage 1 (full 8 inputs), butterfly index p
__device__ __forceinline__ void tstage1(float2 a0, float2 a1, float2 a2, float2 a3,
    float2 a4, float2 a5, float2 a6, float2 a7, float2* __restrict__ S, int p,
    float2 w1,float2 w2,float2 w3,float2 w4,float2 w5,float2 w6,float2 w7) {
    dft8_fwd(a0,a1,a2,a3,a4,a5,a6,a7);
    S[PAD(p)]        = a0;
    S[PAD(p + 1024)] = cmul(a1, w1);
    S[PAD(p + 2048)] = cmul(a2, w2);
    S[PAD(p + 3072)] = cmul(a3, w3);
    S[PAD(p + 4096)] = cmul(a4, w4);
    S[PAD(p + 5120)] = cmul(a5, w5);
    S[PAD(p + 6144)] = cmul(a6, w6);
    S[PAD(p + 7168)] = cmul(a7, w7);
}

// final inverse stage (L=8192): only time outputs j=0..3 of butterfly p
__device__ __forceinline__ void inv_final(const float2* __restrict__ S, int p,
    float2 w1,float2 w2,float2 w3,float2 w4,float2 w5,float2 w6,float2 w7,
    float2& r0, float2& r1, float2& r2, float2& r3) {
    float2 z0 = S[PAD(p)];
    float2 z1 = cmul(S[PAD(p + 1024)], w1);
    float2 z2 = cmul(S[PAD(p + 2048)], w2);
    float2 z3 = cmul(S[PAD(p + 3072)], w3);
    float2 z4 = cmul(S[PAD(p + 4096)], w4);
    float2 z5 = cmul(S[PAD(p + 5120)], w5);
    float2 z6 = cmul(S[PAD(p + 6144)], w6);
    float2 z7 = cmul(S[PAD(p + 7168)], w7);
    float2 s02 = cadd(z0,z4), d02 = csub(z0,z4), s13 = cadd(z2,z6), d13 = csub(z2,z6);
    float2 P0 = cadd(s02,s13), P2 = csub(s02,s13);
    float2 P1 = cadd(d02, mulposi(d13)), P3 = csub(d02, mulposi(d13));
    float2 t02 = cadd(z1,z5), u02 = csub(z1,z5), t13 = cadd(z3,z7), u13 = csub(z3,z7);
    float2 Q0 = cadd(t02,t13), Q2 = csub(t02,t13);
    float2 Q1 = cadd(u02, mulposi(u13)), Q3 = csub(u02, mulposi(u13));
    r0 = cadd(P0, Q0);
    r1 = cadd(P1, mulv81(Q1));
    r2 = cadd(P2, mulposi(Q2));
    r3 = cadd(P3, mulv83(Q3));
}

// fwd-r2 + conj-symmetry sep + Tsep mul + inv-r2 (regs across one barrier), 512 thr
__device__ __forceinline__ void sep_conv(float2* __restrict__ S,
                                         const float4* __restrict__ tb, int tid) {
    float2 Wr[16];
    #pragma unroll
    for (int it = 0; it < 8; ++it) {
        int u = tid + (it << 9);
        int K = rev8_12(u);
        int v = rev8_12((4096 - K) & 4095);
        float2 V0 = S[PAD(2*u)], V1 = S[PAD(2*u + 1)];
        float2 Za = cadd(V0, V1), Zb = csub(V0, V1);
        float2 Zc, Zd;
        if (u == 0) { Zc = Zb; Zd = Za; }
        else {
            float2 U0 = S[PAD(2*v)], U1 = S[PAD(2*v + 1)];
            Zc = cadd(U0, U1); Zd = csub(U0, U1);
        }
        float4 t0 = tb[2*u], t1 = tb[2*u + 1];
        float2 Xd = make_float2((Za.x + Zd.x) * 0.5f, (Za.y - Zd.y) * 0.5f);
        float2 Xe = make_float2((Za.y + Zd.y) * 0.5f, (Zd.x - Za.x) * 0.5f);
        float2 A0 = cmul(Xd, make_float2(t0.x, t0.y));
        float2 B0 = cmul(Xe, make_float2(t0.z, t0.w));
        float2 Q0 = make_float2(A0.x - B0.y, A0.y + B0.x);
        float2 Yd = make_float2((Zb.x + Zc.x) * 0.5f, (Zb.y - Zc.y) * 0.5f);
        float2 Ye = make_float2((Zb.y + Zc.y) * 0.5f, (Zc.x - Zb.x) * 0.5f);
        float2 A1 = cmul(Yd, make_float2(t1.x, t1.y));
        float2 B1 = cmul(Ye, make_float2(t1.z, t1.w));
        float2 Q1 = make_float2(A1.x - B1.y, A1.y + B1.x);
        Wr[2*it]     = cadd(Q0, Q1);
        Wr[2*it + 1] = csub(Q0, Q1);
    }
    __syncthreads();
    #pragma unroll
    for (int it = 0; it < 8; ++it) {
        int u = tid + (it << 9);
        S[PAD(2*u)]     = Wr[2*it];
        S[PAD(2*u + 1)] = Wr[2*it + 1];
    }
    __syncthreads();
}

// ---------------- T precompute: 256 blocks x 1024 thr, 1 pair each -------------
__global__ __launch_bounds__(TTHR, 4) void tsep_k(
    const float* __restrict__ T, float4* __restrict__ Tsep)
{
    extern __shared__ float2 S[];
    const int tid = threadIdx.x;
    const int c = blockIdx.x;              // pair [0,256)
    const float* tp = T + (c << 1);

    {
        float2 a0 = *(const float2*)(tp + (size_t)(tid       ) * 512);
        float2 a1 = *(const float2*)(tp + (size_t)(tid + 1024) * 512);
        float2 a2 = *(const float2*)(tp + (size_t)(tid + 2048) * 512);
        float2 a3 = *(const float2*)(tp + (size_t)(tid + 3072) * 512);
        float2 a4 = *(const float2*)(tp + (size_t)(tid + 4096) * 512);
        float2 a5 = *(const float2*)(tp + (size_t)(tid + 5120) * 512);
        float2 a6 = *(const float2*)(tp + (size_t)(tid + 6144) * 512);
        float2 a7 = *(const float2*)(tp + (size_t)(tid + 7168) * 512);
        float sn, cs;
        __sincosf(-TWO_PI * (float)tid / 8192.0f, &sn, &cs);
        float2 w1 = make_float2(cs, sn);
        WCHAIN(w1, w2,w3,w4,w5,w6,w7);
        tstage1(a0,a1,a2,a3,a4,a5,a6,a7, S, tid, w1,w2,w3,w4,w5,w6,w7);
    }
    __syncthreads();
    fwd_stage_1b<7>(S, tid); __syncthreads();
    fwd_stage_1b<4>(S, tid); __syncthreads();
    fwd_stage_1b<1>(S, tid); __syncthreads();

    const float sc = 0.5f / (float)NFFT;
    float4* tb = Tsep + (size_t)c * NFFT;
    #pragma unroll
    for (int it = 0; it < 4; ++it) {
        int u = tid + (it << 10);
        int K = rev8_12(u);
        int v = rev8_12((4096 - K) & 4095);
        float2 V0 = S[PAD(2*u)], V1 = S[PAD(2*u + 1)];
        float2 Za = cadd(V0, V1), Zb = csub(V0, V1);
        float2 Zc, Zd;
        if (u == 0) { Zc = Zb; Zd = Za; }
        else {
            float2 U0 = S[PAD(2*v)], U1 = S[PAD(2*v + 1)];
            Zc = cadd(U0, U1); Zd = csub(U0, U1);
        }
        tb[2*u]     = make_float4((Za.x + Zd.x) * sc, (Za.y - Zd.y) * sc,
                                  (Za.y + Zd.y) * sc, (Zd.x - Za.x) * sc);
        tb[2*u + 1] = make_float4((Zb.x + Zc.x) * sc, (Zb.y - Zc.y) * sc,
                                  (Zb.y + Zc.y) * sc, (Zc.x - Zb.x) * sc);
    }
}

// ---------------- main conv: 1024 blocks x 512 thr, 2 blocks/CU, 1 pair each ----
__global__ __launch_bounds__(CTHR, 4) void fftconv7(
    const float* __restrict__ X, const float4* __restrict__ Tsep,
    float* __restrict__ O)
{
    extern __shared__ float2 S[];
    const int tid = threadIdx.x;

    // swizzle: lbid = 64k + 8x + w  (x = XCD). The 8 blocks sharing each 64B
    // output line (same b, pairs 8c..8c+7) AND the 4 b-variants of one Tsep
    // panel (lbid += 256 keeps x) land on one XCD.
    int h = blockIdx.x;                    // [0,1024)
    int x = h & 7;
    int r = h >> 3;                        // [0,128)
    int k = r >> 3, w = r & 7;
    int lbid = (k << 6) + (x << 3) + w;    // bijective on [0,1024)
    const int b = lbid >> 8;
    const int c = lbid & 255;
    const float* xp = X + (size_t)b * 4096 * 512 + (c << 1);

    const float2 C512F = make_float2(0.92387953251128675613f, -0.38268343236508977173f); // e^{-i pi/8}
    const float2 C512I = make_float2(0.92387953251128675613f,  0.38268343236508977173f); // e^{+i pi/8}

    // ---- stage 1 fused with load (inputs 4..7 of each butterfly are zero) ----
    {
        float2 a0 = *(const float2*)(xp + (size_t)(tid       ) * 512);
        float2 a1 = *(const float2*)(xp + (size_t)(tid + 1024) * 512);
        float2 a2 = *(const float2*)(xp + (size_t)(tid + 2048) * 512);
        float2 a3 = *(const float2*)(xp + (size_t)(tid + 3072) * 512);
        float2 b0 = *(const float2*)(xp + (size_t)(tid +  512) * 512);
        float2 b1 = *(const float2*)(xp + (size_t)(tid + 1536) * 512);
        float2 b2 = *(const float2*)(xp + (size_t)(tid + 2560) * 512);
        float2 b3 = *(const float2*)(xp + (size_t)(tid + 3584) * 512);
        float sn, cs;
        __sincosf(-TWO_PI * (float)tid / 8192.0f, &sn, &cs);
        float2 w1 = make_float2(cs, sn);
        WCHAIN(w1, w2,w3,w4,w5,w6,w7);
        xstage1(a0, a1, a2, a3, S, tid, w1,w2,w3,w4,w5,w6,w7);
        float2 v1 = cmul(w1, C512F);
        WCHAIN(v1, v2,v3,v4,v5,v6,v7);
        xstage1(b0, b1, b2, b3, S, tid + 512, v1,v2,v3,v4,v5,v6,v7);
    }
    __syncthreads();
    fwd_stage_dual<7>(S, tid); __syncthreads();
    fwd_stage_dual<4>(S, tid); __syncthreads();
    fwd_stage_dual<1>(S, tid); __syncthreads();

    sep_conv(S, Tsep + (size_t)c * NFFT, tid);    // internal barriers

    inv_stage_dual<1>(S, tid); __syncthreads();
    inv_stage_dual<4>(S, tid); __syncthreads();
    inv_stage_dual<7>(S, tid); __syncthreads();

    // ---- final inverse stage fused with store (times j*1024 + {tid, tid+512}) ----
    {
        float sn, cs;
        __sincosf(TWO_PI * (float)tid / 8192.0f, &sn, &cs);
        float2 w1 = make_float2(cs, sn);
        WCHAIN(w1, w2,w3,w4,w5,w6,w7);
        float* op = O + (size_t)b * 4096 * 512 + (c << 1);
        float2 r0, r1, r2, r3;
        inv_final(S, tid, w1,w2,w3,w4,w5,w6,w7, r0, r1, r2, r3);
        *(float2*)(op + (size_t)(tid       ) * 512) = r0;
        *(float2*)(op + (size_t)(tid + 1024) * 512) = r1;
        *(float2*)(op + (size_t)(tid + 2048) * 512) = r2;
        *(float2*)(op + (size_t)(tid + 3072) * 512) = r3;
        float2 v1 = cmul(w1, C512I);
        WCHAIN(v1, v2,v3,v4,v5,v6,v7);
        inv_final(S, tid + 512, v1,v2,v3,v4,v5,v6,v7, r0, r1, r2, r3);
        *(float2*)(op + (size_t)(tid +  512) * 512) = r0;
        *(float2*)(op + (size_t)(tid + 1536) * 512) = r1;
        *(float2*)(op + (size_t)(tid + 2560) * 512) = r2;
        *(float2*)(op + (size_t)(tid + 3584) * 512) = r3;
    }
}

extern "C" void kernel_launch(void* const* d_in, const int* in_sizes, int n_in,
                              void* d_out, int out_size, void* d_ws, size_t ws_size,
                              hipStream_t stream)
{
    const float* x = (const float*)d_in[0];   // (4, 4096, 512)
    const float* t = (const float*)d_in[1];   // (8192, 512)
    float* out = (float*)d_out;               // (4, 4096, 512)
    float4* tsep = (float4*)d_ws;             // 256*8192*16 B = 32 MB

    const int lds = (int)(LDS_ELEMS * sizeof(float2));   // 69632
    (void)hipFuncSetAttribute((const void*)tsep_k,
                              hipFuncAttributeMaxDynamicSharedMemorySize, lds);
    (void)hipFuncSetAttribute((const void*)fftconv7,
                              hipFuncAttributeMaxDynamicSharedMemorySize, lds);

    tsep_k<<<256, TTHR, lds, stream>>>(t, tsep);
    fftconv7<<<1024, CTHR, lds, stream>>>(x, tsep, out);
}

// Round 9
// 97.674 us; speedup vs baseline: 3.0322x; 1.1494x over previous
//
#include <hip/hip_runtime.h>
#include <math.h>

// Round 9: revert to verified round-5 conv + two minimal changes.
//   1. fftconv5: __launch_bounds__(1024, 2) -> VGPR cap 128 (was 64).
//      LDS (139 KB) caps occupancy at 1 block/CU = 4 waves/SIMD, which
//      permits 128 VGPR/wave free (4x128 = 512/SIMD file). Empirical rule
//      from R4/R5/R7: cap = 256/waves_arg, compiler uses all of it.
//   2. tsep: round-7's verified 256-block x 1024-thr full-GPU kernel
//      (radix-8, single 69.6 KB buffer) instead of the 128-block version.
// FFT: register radix-8, 8192 = 8^4*2; slot perm = octal digit reversal.

#define NFFT 8192
#define NTHR 1024
#define PAD(i) ((i) + ((i) >> 4))
#define LDS_ELEMS (NFFT + (NFFT >> 4))          // 8704 float2 = 69632 B per buffer
#define TWO_PI 6.28318530717958647692f
#define RSQRT2 0.70710678118654752440f

__device__ __forceinline__ float2 cadd(float2 a, float2 b){ return make_float2(a.x+b.x, a.y+b.y); }
__device__ __forceinline__ float2 csub(float2 a, float2 b){ return make_float2(a.x-b.x, a.y-b.y); }
__device__ __forceinline__ float2 cmul(float2 a, float2 b){ return make_float2(a.x*b.x - a.y*b.y, a.x*b.y + a.y*b.x); }
__device__ __forceinline__ float2 mulnegi(float2 a){ return make_float2(a.y, -a.x); }   // * (-i)
__device__ __forceinline__ float2 mulposi(float2 a){ return make_float2(-a.y, a.x); }   // * (+i)
__device__ __forceinline__ float2 mulw81(float2 z){ return make_float2(RSQRT2*(z.x+z.y), RSQRT2*(z.y-z.x)); }  // e^{-i pi/4}
__device__ __forceinline__ float2 mulw83(float2 z){ return make_float2(RSQRT2*(z.y-z.x), -RSQRT2*(z.x+z.y)); } // e^{-i 3pi/4}
__device__ __forceinline__ float2 mulv81(float2 z){ return make_float2(RSQRT2*(z.x-z.y), RSQRT2*(z.x+z.y)); }  // e^{+i pi/4}
__device__ __forceinline__ float2 mulv83(float2 z){ return make_float2(-RSQRT2*(z.x+z.y), RSQRT2*(z.x-z.y)); } // e^{+i 3pi/4}

__device__ __forceinline__ int rev8_12(int u) {   // 4-octal-digit reversal, involution
    return ((u & 7) << 9) | (((u >> 3) & 7) << 6) | (((u >> 6) & 7) << 3) | ((u >> 9) & 7);
}

__device__ __forceinline__ void dft8_fwd(float2& a0, float2& a1, float2& a2, float2& a3,
                                         float2& a4, float2& a5, float2& a6, float2& a7) {
    float2 s02 = cadd(a0,a4), d02 = csub(a0,a4), s13 = cadd(a2,a6), d13 = csub(a2,a6);
    float2 E0 = cadd(s02,s13), E2 = csub(s02,s13);
    float2 E1 = cadd(d02, mulnegi(d13)), E3 = csub(d02, mulnegi(d13));
    float2 t02 = cadd(a1,a5), u02 = csub(a1,a5), t13 = cadd(a3,a7), u13 = csub(a3,a7);
    float2 O0 = cadd(t02,t13), O2 = csub(t02,t13);
    float2 O1 = cadd(u02, mulnegi(u13)), O3 = csub(u02, mulnegi(u13));
    float2 W1 = mulw81(O1), W2 = mulnegi(O2), W3 = mulw83(O3);
    a0 = cadd(E0,O0); a4 = csub(E0,O0);
    a1 = cadd(E1,W1); a5 = csub(E1,W1);
    a2 = cadd(E2,W2); a6 = csub(E2,W2);
    a3 = cadd(E3,W3); a7 = csub(E3,W3);
}

__device__ __forceinline__ void dft8_inv(float2& a0, float2& a1, float2& a2, float2& a3,
                                         float2& a4, float2& a5, float2& a6, float2& a7) {
    float2 s02 = cadd(a0,a4), d02 = csub(a0,a4), s13 = cadd(a2,a6), d13 = csub(a2,a6);
    float2 P0 = cadd(s02,s13), P2 = csub(s02,s13);
    float2 P1 = cadd(d02, mulposi(d13)), P3 = csub(d02, mulposi(d13));
    float2 t02 = cadd(a1,a5), u02 = csub(a1,a5), t13 = cadd(a3,a7), u13 = csub(a3,a7);
    float2 Q0 = cadd(t02,t13), Q2 = csub(t02,t13);
    float2 Q1 = cadd(u02, mulposi(u13)), Q3 = csub(u02, mulposi(u13));
    float2 W1 = mulv81(Q1), W2 = mulposi(Q2), W3 = mulv83(Q3);
    a0 = cadd(P0,Q0); a4 = csub(P0,Q0);
    a1 = cadd(P1,W1); a5 = csub(P1,W1);
    a2 = cadd(P2,W2); a6 = csub(P2,W2);
    a3 = cadd(P3,W3); a7 = csub(P3,W3);
}

// one radix-8 fwd butterfly on buffer S (indices/twiddles from caller)
__device__ __forceinline__ void fwd_one(float2* __restrict__ S,
    int i0,int i1,int i2,int i3,int i4,int i5,int i6,int i7,
    float2 w1,float2 w2,float2 w3,float2 w4,float2 w5,float2 w6,float2 w7) {
    float2 a0=S[i0],a1=S[i1],a2=S[i2],a3=S[i3],a4=S[i4],a5=S[i5],a6=S[i6],a7=S[i7];
    dft8_fwd(a0,a1,a2,a3,a4,a5,a6,a7);
    S[i0]=a0;           S[i1]=cmul(a1,w1); S[i2]=cmul(a2,w2); S[i3]=cmul(a3,w3);
    S[i4]=cmul(a4,w4);  S[i5]=cmul(a5,w5); S[i6]=cmul(a6,w6); S[i7]=cmul(a7,w7);
}

__device__ __forceinline__ void inv_one(float2* __restrict__ S,
    int i0,int i1,int i2,int i3,int i4,int i5,int i6,int i7,
    float2 w1,float2 w2,float2 w3,float2 w4,float2 w5,float2 w6,float2 w7) {
    float2 a0=S[i0];
    float2 a1=cmul(S[i1],w1), a2=cmul(S[i2],w2), a3=cmul(S[i3],w3), a4=cmul(S[i4],w4),
           a5=cmul(S[i5],w5), a6=cmul(S[i6],w6), a7=cmul(S[i7],w7);
    dft8_inv(a0,a1,a2,a3,a4,a5,a6,a7);
    S[i0]=a0; S[i1]=a1; S[i2]=a2; S[i3]=a3; S[i4]=a4; S[i5]=a5; S[i6]=a6; S[i7]=a7;
}

#define WCHAIN(w1, w2,w3,w4,w5,w6,w7) \
    float2 w2 = cmul(w1,w1), w3 = cmul(w2,w1), w4 = cmul(w2,w2), \
           w5 = cmul(w4,w1), w6 = cmul(w4,w2), w7 = cmul(w4,w3)

// ---- dual-buffer stages (conv, 1024 threads, one butterfly per buffer) ----
template<int LQ>
__device__ __forceinline__ void fwd_stage2(float2* __restrict__ S0, float2* __restrict__ S1, int tid) {
    const int q = 1 << LQ;
    const int m = tid & (q - 1);
    const int B = ((tid >> LQ) << (LQ + 3)) + m;
    const int i0=PAD(B),i1=PAD(B+q),i2=PAD(B+2*q),i3=PAD(B+3*q),
              i4=PAD(B+4*q),i5=PAD(B+5*q),i6=PAD(B+6*q),i7=PAD(B+7*q);
    float sn, cs;
    __sincosf(-TWO_PI * (float)m / (float)(q << 3), &sn, &cs);
    float2 w1 = make_float2(cs, sn);
    WCHAIN(w1, w2,w3,w4,w5,w6,w7);
    fwd_one(S0,i0,i1,i2,i3,i4,i5,i6,i7,w1,w2,w3,w4,w5,w6,w7);
    fwd_one(S1,i0,i1,i2,i3,i4,i5,i6,i7,w1,w2,w3,w4,w5,w6,w7);
}

template<int LQ>
__device__ __forceinline__ void inv_stage2(float2* __restrict__ S0, float2* __restrict__ S1, int tid) {
    const int q = 1 << LQ;
    const int m = tid & (q - 1);
    const int B = ((tid >> LQ) << (LQ + 3)) + m;
    const int i0=PAD(B),i1=PAD(B+q),i2=PAD(B+2*q),i3=PAD(B+3*q),
              i4=PAD(B+4*q),i5=PAD(B+5*q),i6=PAD(B+6*q),i7=PAD(B+7*q);
    float sn, cs;
    __sincosf(TWO_PI * (float)m / (float)(q << 3), &sn, &cs);
    float2 w1 = make_float2(cs, sn);
    WCHAIN(w1, w2,w3,w4,w5,w6,w7);
    inv_one(S0,i0,i1,i2,i3,i4,i5,i6,i7,w1,w2,w3,w4,w5,w6,w7);
    inv_one(S1,i0,i1,i2,i3,i4,i5,i6,i7,w1,w2,w3,w4,w5,w6,w7);
}

// ---- single-buffer stage (tsep, 1024 threads) ----
template<int LQ>
__device__ __forceinline__ void fwd_stage_1b(float2* __restrict__ S, int tid) {
    const int q = 1 << LQ;
    const int m = tid & (q - 1);
    const int B = ((tid >> LQ) << (LQ + 3)) + m;
    const int i0=PAD(B),i1=PAD(B+q),i2=PAD(B+2*q),i3=PAD(B+3*q),
              i4=PAD(B+4*q),i5=PAD(B+5*q),i6=PAD(B+6*q),i7=PAD(B+7*q);
    float sn, cs;
    __sincosf(-TWO_PI * (float)m / (float)(q << 3), &sn, &cs);
    float2 w1 = make_float2(cs, sn);
    WCHAIN(w1, w2,w3,w4,w5,w6,w7);
    fwd_one(S,i0,i1,i2,i3,i4,i5,i6,i7,w1,w2,w3,w4,w5,w6,w7);
}

// x stage 1 (L=8192) with inputs 4..7 zero; write to S with twiddle chain
__device__ __forceinline__ void xstage1(float2 a0, float2 a1, float2 a2, float2 a3,
    float2* __restrict__ S, int tid,
    float2 w1,float2 w2,float2 w3,float2 w4,float2 w5,float2 w6,float2 w7) {
    float2 s02 = cadd(a0,a2), d02 = csub(a0,a2), s13 = cadd(a1,a3), d13 = csub(a1,a3);
    float2 F0 = cadd(s02,s13), F2 = csub(s02,s13);
    float2 F1 = cadd(d02, mulnegi(d13)), F3 = csub(d02, mulnegi(d13));
    float2 g1 = mulw81(a1), g2 = mulnegi(a2), g3 = mulw83(a3);
    float2 gs02 = cadd(a0,g2), gd02 = csub(a0,g2), gs13 = cadd(g1,g3), gd13 = csub(g1,g3);
    float2 G0 = cadd(gs02,gs13), G2 = csub(gs02,gs13);
    float2 G1 = cadd(gd02, mulnegi(gd13)), G3 = csub(gd02, mulnegi(gd13));
    S[PAD(tid)]        = F0;
    S[PAD(tid + 1024)] = cmul(G0, w1);
    S[PAD(tid + 2048)] = cmul(F1, w2);
    S[PAD(tid + 3072)] = cmul(G1, w3);
    S[PAD(tid + 4096)] = cmul(F2, w4);
    S[PAD(tid + 5120)] = cmul(G2, w5);
    S[PAD(tid + 6144)] = cmul(F3, w6);
    S[PAD(tid + 7168)] = cmul(G3, w7);
}

// t stage 1 (full 8 inputs)
__device__ __forceinline__ void tstage1(float2 a0, float2 a1, float2 a2, float2 a3,
    float2 a4, float2 a5, float2 a6, float2 a7, float2* __restrict__ S, int tid,
    float2 w1,float2 w2,float2 w3,float2 w4,float2 w5,float2 w6,float2 w7) {
    dft8_fwd(a0,a1,a2,a3,a4,a5,a6,a7);
    S[PAD(tid)]        = a0;
    S[PAD(tid + 1024)] = cmul(a1, w1);
    S[PAD(tid + 2048)] = cmul(a2, w2);
    S[PAD(tid + 3072)] = cmul(a3, w3);
    S[PAD(tid + 4096)] = cmul(a4, w4);
    S[PAD(tid + 5120)] = cmul(a5, w5);
    S[PAD(tid + 6144)] = cmul(a6, w6);
    S[PAD(tid + 7168)] = cmul(a7, w7);
}

// final inverse stage (L=8192): compute time outputs j=0..3 only
__device__ __forceinline__ void inv_final(const float2* __restrict__ S, int tid,
    float2 w1,float2 w2,float2 w3,float2 w4,float2 w5,float2 w6,float2 w7,
    float2& r0, float2& r1, float2& r2, float2& r3) {
    float2 z0 = S[PAD(tid)];
    float2 z1 = cmul(S[PAD(tid + 1024)], w1);
    float2 z2 = cmul(S[PAD(tid + 2048)], w2);
    float2 z3 = cmul(S[PAD(tid + 3072)], w3);
    float2 z4 = cmul(S[PAD(tid + 4096)], w4);
    float2 z5 = cmul(S[PAD(tid + 5120)], w5);
    float2 z6 = cmul(S[PAD(tid + 6144)], w6);
    float2 z7 = cmul(S[PAD(tid + 7168)], w7);
    float2 s02 = cadd(z0,z4), d02 = csub(z0,z4), s13 = cadd(z2,z6), d13 = csub(z2,z6);
    float2 P0 = cadd(s02,s13), P2 = csub(s02,s13);
    float2 P1 = cadd(d02, mulposi(d13)), P3 = csub(d02, mulposi(d13));
    float2 t02 = cadd(z1,z5), u02 = csub(z1,z5), t13 = cadd(z3,z7), u13 = csub(z3,z7);
    float2 Q0 = cadd(t02,t13), Q2 = csub(t02,t13);
    float2 Q1 = cadd(u02, mulposi(u13)), Q3 = csub(u02, mulposi(u13));
    r0 = cadd(P0, Q0);
    r1 = cadd(P1, mulv81(Q1));
    r2 = cadd(P2, mulposi(Q2));
    r3 = cadd(P3, mulv83(Q3));
}

// fwd-r2 + conj-symmetry separation + Tsep mul + inv-r2, regs across 1 barrier
__device__ __forceinline__ void sep_pass(float2* __restrict__ S,
                                         const float4* __restrict__ tb, int tid) {
    float2 Wr[8];
    #pragma unroll
    for (int it = 0; it < 4; ++it) {
        int u = tid + (it << 10);
        int K = rev8_12(u);
        int v = rev8_12((4096 - K) & 4095);
        float2 V0 = S[PAD(2*u)], V1 = S[PAD(2*u + 1)];
        float2 Za = cadd(V0, V1), Zb = csub(V0, V1);
        float2 Zc, Zd;
        if (u == 0) { Zc = Zb; Zd = Za; }
        else {
            float2 U0 = S[PAD(2*v)], U1 = S[PAD(2*v + 1)];
            Zc = cadd(U0, U1); Zd = csub(U0, U1);
        }
        float4 t0 = tb[2*u], t1 = tb[2*u + 1];
        float2 Xd = make_float2((Za.x + Zd.x) * 0.5f, (Za.y - Zd.y) * 0.5f);
        float2 Xe = make_float2((Za.y + Zd.y) * 0.5f, (Zd.x - Za.x) * 0.5f);
        float2 A0 = cmul(Xd, make_float2(t0.x, t0.y));
        float2 B0 = cmul(Xe, make_float2(t0.z, t0.w));
        float2 Q0 = make_float2(A0.x - B0.y, A0.y + B0.x);
        float2 Yd = make_float2((Zb.x + Zc.x) * 0.5f, (Zb.y - Zc.y) * 0.5f);
        float2 Ye = make_float2((Zb.y + Zc.y) * 0.5f, (Zc.x - Zb.x) * 0.5f);
        float2 A1 = cmul(Yd, make_float2(t1.x, t1.y));
        float2 B1 = cmul(Ye, make_float2(t1.z, t1.w));
        float2 Q1 = make_float2(A1.x - B1.y, A1.y + B1.x);
        Wr[2*it]     = cadd(Q0, Q1);
        Wr[2*it + 1] = csub(Q0, Q1);
    }
    __syncthreads();
    #pragma unroll
    for (int it = 0; it < 4; ++it) {
        int u = tid + (it << 10);
        S[PAD(2*u)]     = Wr[2*it];
        S[PAD(2*u + 1)] = Wr[2*it + 1];
    }
}

// T-spectrum separation + store for one buffer
__device__ __forceinline__ void tsep_tail(const float2* __restrict__ S,
                                          float4* __restrict__ tb, int tid) {
    const float sc = 0.5f / (float)NFFT;
    #pragma unroll
    for (int it = 0; it < 4; ++it) {
        int u = tid + (it << 10);
        int K = rev8_12(u);
        int v = rev8_12((4096 - K) & 4095);
        float2 V0 = S[PAD(2*u)], V1 = S[PAD(2*u + 1)];
        float2 Za = cadd(V0, V1), Zb = csub(V0, V1);
        float2 Zc, Zd;
        if (u == 0) { Zc = Zb; Zd = Za; }
        else {
            float2 U0 = S[PAD(2*v)], U1 = S[PAD(2*v + 1)];
            Zc = cadd(U0, U1); Zd = csub(U0, U1);
        }
        tb[2*u]     = make_float4((Za.x + Zd.x) * sc, (Za.y - Zd.y) * sc,
                                  (Za.y + Zd.y) * sc, (Zd.x - Za.x) * sc);
        tb[2*u + 1] = make_float4((Zb.x + Zc.x) * sc, (Zb.y - Zc.y) * sc,
                                  (Zb.y + Zc.y) * sc, (Zc.x - Zb.x) * sc);
    }
}

// ---------------- T precompute: 256 blocks x 1024 thr, 1 pair each -------------
__global__ __launch_bounds__(NTHR, 4) void tsep_k(
    const float* __restrict__ T, float4* __restrict__ Tsep)
{
    extern __shared__ float2 S[];
    const int tid = threadIdx.x;
    const int c = blockIdx.x;              // pair [0,256)
    const float* tp = T + (c << 1);

    {
        float2 a0 = *(const float2*)(tp + (size_t)(tid       ) * 512);
        float2 a1 = *(const float2*)(tp + (size_t)(tid + 1024) * 512);
        float2 a2 = *(const float2*)(tp + (size_t)(tid + 2048) * 512);
        float2 a3 = *(const float2*)(tp + (size_t)(tid + 3072) * 512);
        float2 a4 = *(const float2*)(tp + (size_t)(tid + 4096) * 512);
        float2 a5 = *(const float2*)(tp + (size_t)(tid + 5120) * 512);
        float2 a6 = *(const float2*)(tp + (size_t)(tid + 6144) * 512);
        float2 a7 = *(const float2*)(tp + (size_t)(tid + 7168) * 512);
        float sn, cs;
        __sincosf(-TWO_PI * (float)tid / 8192.0f, &sn, &cs);
        float2 w1 = make_float2(cs, sn);
        WCHAIN(w1, w2,w3,w4,w5,w6,w7);
        tstage1(a0,a1,a2,a3,a4,a5,a6,a7, S, tid, w1,w2,w3,w4,w5,w6,w7);
    }
    __syncthreads();
    fwd_stage_1b<7>(S, tid); __syncthreads();
    fwd_stage_1b<4>(S, tid); __syncthreads();
    fwd_stage_1b<1>(S, tid); __syncthreads();

    tsep_tail(S, Tsep + (size_t)c * NFFT, tid);
}

// ---------------- main conv: 512 blocks x 1024 thr, 4 channels each ------------
__global__ __launch_bounds__(NTHR, 2) void fftconv5(
    const float* __restrict__ X, const float4* __restrict__ Tsep,
    float* __restrict__ O)
{
    extern __shared__ float2 L[];
    float2* S0 = L;
    float2* S1 = L + LDS_ELEMS;
    const int tid = threadIdx.x;

    // XCD swizzle: 4 consecutive-g blocks (sharing 64B lines) per XCD
    int h = blockIdx.x;                    // [0,512)
    int xcd = h & 7, sl = h >> 3;
    int lbid = ((sl >> 2) << 5) | (xcd << 2) | (sl & 3);   // bijective on [0,512)
    const int b = lbid >> 7;
    const int g = lbid & 127;
    const float* xp = X + (size_t)b * 4096 * 512 + (g << 2);

    float4 l0 = *(const float4*)(xp + (size_t)(tid       ) * 512);
    float4 l1 = *(const float4*)(xp + (size_t)(tid + 1024) * 512);
    float4 l2 = *(const float4*)(xp + (size_t)(tid + 2048) * 512);
    float4 l3 = *(const float4*)(xp + (size_t)(tid + 3072) * 512);
    {
        float sn, cs;
        __sincosf(-TWO_PI * (float)tid / 8192.0f, &sn, &cs);
        float2 w1 = make_float2(cs, sn);
        float2 w2 = cmul(w1,w1), w3 = cmul(w2,w1), w4 = cmul(w2,w2),
               w5 = cmul(w4,w1), w6 = cmul(w4,w2), w7 = cmul(w4,w3);
        xstage1(make_float2(l0.x,l0.y), make_float2(l1.x,l1.y),
                make_float2(l2.x,l2.y), make_float2(l3.x,l3.y), S0, tid,
                w1,w2,w3,w4,w5,w6,w7);
        xstage1(make_float2(l0.z,l0.w), make_float2(l1.z,l1.w),
                make_float2(l2.z,l2.w), make_float2(l3.z,l3.w), S1, tid,
                w1,w2,w3,w4,w5,w6,w7);
    }
    __syncthreads();
    fwd_stage2<7>(S0, S1, tid); __syncthreads();
    fwd_stage2<4>(S0, S1, tid); __syncthreads();
    fwd_stage2<1>(S0, S1, tid); __syncthreads();

    sep_pass(S0, Tsep + (size_t)(2*g)     * NFFT, tid);   // internal barrier
    sep_pass(S1, Tsep + (size_t)(2*g + 1) * NFFT, tid);   // internal barrier
    __syncthreads();

    inv_stage2<1>(S0, S1, tid); __syncthreads();
    inv_stage2<4>(S0, S1, tid); __syncthreads();
    inv_stage2<7>(S0, S1, tid); __syncthreads();

    {
        float sn, cs;
        __sincosf(TWO_PI * (float)tid / 8192.0f, &sn, &cs);
        float2 w1 = make_float2(cs, sn);
        float2 w2 = cmul(w1,w1), w3 = cmul(w2,w1), w4 = cmul(w2,w2),
               w5 = cmul(w4,w1), w6 = cmul(w4,w2), w7 = cmul(w4,w3);
        float2 p0,p1,p2,p3, q0,q1,q2,q3;
        inv_final(S0, tid, w1,w2,w3,w4,w5,w6,w7, p0,p1,p2,p3);
        inv_final(S1, tid, w1,w2,w3,w4,w5,w6,w7, q0,q1,q2,q3);
        float* op = O + (size_t)b * 4096 * 512 + (g << 2);
        *(float4*)(op + (size_t)(tid       ) * 512) = make_float4(p0.x,p0.y,q0.x,q0.y);
        *(float4*)(op + (size_t)(tid + 1024) * 512) = make_float4(p1.x,p1.y,q1.x,q1.y);
        *(float4*)(op + (size_t)(tid + 2048) * 512) = make_float4(p2.x,p2.y,q2.x,q2.y);
        *(float4*)(op + (size_t)(tid + 3072) * 512) = make_float4(p3.x,p3.y,q3.x,q3.y);
    }
}

extern "C" void kernel_launch(void* const* d_in, const int* in_sizes, int n_in,
                              void* d_out, int out_size, void* d_ws, size_t ws_size,
                              hipStream_t stream)
{
    const float* x = (const float*)d_in[0];   // (4, 4096, 512)
    const float* t = (const float*)d_in[1];   // (8192, 512)
    float* out = (float*)d_out;               // (4, 4096, 512)
    float4* tsep = (float4*)d_ws;             // 256*8192*16 B = 32 MB

    const int lds1 = (int)(LDS_ELEMS * sizeof(float2));      // 69632
    const int lds2 = (int)(2 * LDS_ELEMS * sizeof(float2));  // 139264
    (void)hipFuncSetAttribute((const void*)tsep_k,
                              hipFuncAttributeMaxDynamicSharedMemorySize, lds1);
    (void)hipFuncSetAttribute((const void*)fftconv5,
                              hipFuncAttributeMaxDynamicSharedMemorySize, lds2);

    tsep_k<<<256, NTHR, lds1, stream>>>(t, tsep);
    fftconv5<<<512, NTHR, lds2, stream>>>(x, tsep, out);
}

// Round 10
// 91.067 us; speedup vs baseline: 3.2522x; 1.0725x over previous
//
#include <hip/hip_runtime.h>
#include <math.h>

// Round 10: even/odd spectral split -> two 4096-point FFTs (8^4, no radix-2).
//   Z[2m]   = FFT4096(z)[m];  Z[2m+1] = FFT4096(z * e^{-2pi i j/8192})[m]
//   o[n]    = IFr4096(Q'e)[n] + e^{+2pi i n/8192} * IFr4096(Q'o)[n]
//   T-side: Te = FFT4096(t_j + t_{j+4096}); To = FFT4096((t_j - t_{j+4096})*mod)
// Wave-local stages: with 512 butterflies/buffer and wave-aligned p, the
// q=64->q=8->q=1 transitions stay within one 64-lane wave (same-wave DS ops
// execute in order) -> no barrier, only a compiler fence. Barriers 11 -> 6.
// conv: 512 blocks x 1024 thr, 4 padded 4096-buffers = 139264 B, float4 I/O.
// tsep: 256 blocks x 1024 thr, 2 buffers (Te,To), same structure.

#define TWO_PI 6.28318530717958647692f
#define RSQRT2 0.70710678118654752440f
#define PADL(i) ((i) + ((i) >> 4))
#define BUF_ELEMS (4096 + 256)            // 4352 float2 = 34816 B per buffer
#define WFENCE() asm volatile("" ::: "memory")

__device__ __forceinline__ float2 cadd(float2 a, float2 b){ return make_float2(a.x+b.x, a.y+b.y); }
__device__ __forceinline__ float2 csub(float2 a, float2 b){ return make_float2(a.x-b.x, a.y-b.y); }
__device__ __forceinline__ float2 cmul(float2 a, float2 b){ return make_float2(a.x*b.x - a.y*b.y, a.x*b.y + a.y*b.x); }
__device__ __forceinline__ float2 mulnegi(float2 a){ return make_float2(a.y, -a.x); }
__device__ __forceinline__ float2 mulposi(float2 a){ return make_float2(-a.y, a.x); }
__device__ __forceinline__ float2 mulw81(float2 z){ return make_float2(RSQRT2*(z.x+z.y), RSQRT2*(z.y-z.x)); }  // e^{-i pi/4}
__device__ __forceinline__ float2 mulw83(float2 z){ return make_float2(RSQRT2*(z.y-z.x), -RSQRT2*(z.x+z.y)); } // e^{-i 3pi/4}
__device__ __forceinline__ float2 mulv81(float2 z){ return make_float2(RSQRT2*(z.x-z.y), RSQRT2*(z.x+z.y)); }  // e^{+i pi/4}
__device__ __forceinline__ float2 mulv83(float2 z){ return make_float2(-RSQRT2*(z.x+z.y), RSQRT2*(z.x-z.y)); } // e^{+i 3pi/4}

__device__ __forceinline__ int rev8_12(int u) {   // 4-octal-digit reversal of 12 bits
    return ((u & 7) << 9) | (((u >> 3) & 7) << 6) | (((u >> 6) & 7) << 3) | ((u >> 9) & 7);
}

__device__ __forceinline__ void dft8_fwd(float2& a0, float2& a1, float2& a2, float2& a3,
                                         float2& a4, float2& a5, float2& a6, float2& a7) {
    float2 s02 = cadd(a0,a4), d02 = csub(a0,a4), s13 = cadd(a2,a6), d13 = csub(a2,a6);
    float2 E0 = cadd(s02,s13), E2 = csub(s02,s13);
    float2 E1 = cadd(d02, mulnegi(d13)), E3 = csub(d02, mulnegi(d13));
    float2 t02 = cadd(a1,a5), u02 = csub(a1,a5), t13 = cadd(a3,a7), u13 = csub(a3,a7);
    float2 O0 = cadd(t02,t13), O2 = csub(t02,t13);
    float2 O1 = cadd(u02, mulnegi(u13)), O3 = csub(u02, mulnegi(u13));
    float2 W1 = mulw81(O1), W2 = mulnegi(O2), W3 = mulw83(O3);
    a0 = cadd(E0,O0); a4 = csub(E0,O0);
    a1 = cadd(E1,W1); a5 = csub(E1,W1);
    a2 = cadd(E2,W2); a6 = csub(E2,W2);
    a3 = cadd(E3,W3); a7 = csub(E3,W3);
}

__device__ __forceinline__ void dft8_inv(float2& a0, float2& a1, float2& a2, float2& a3,
                                         float2& a4, float2& a5, float2& a6, float2& a7) {
    float2 s02 = cadd(a0,a4), d02 = csub(a0,a4), s13 = cadd(a2,a6), d13 = csub(a2,a6);
    float2 P0 = cadd(s02,s13), P2 = csub(s02,s13);
    float2 P1 = cadd(d02, mulposi(d13)), P3 = csub(d02, mulposi(d13));
    float2 t02 = cadd(a1,a5), u02 = csub(a1,a5), t13 = cadd(a3,a7), u13 = csub(a3,a7);
    float2 Q0 = cadd(t02,t13), Q2 = csub(t02,t13);
    float2 Q1 = cadd(u02, mulposi(u13)), Q3 = csub(u02, mulposi(u13));
    float2 W1 = mulv81(Q1), W2 = mulposi(Q2), W3 = mulv83(Q3);
    a0 = cadd(P0,Q0); a4 = csub(P0,Q0);
    a1 = cadd(P1,W1); a5 = csub(P1,W1);
    a2 = cadd(P2,W2); a6 = csub(P2,W2);
    a3 = cadd(P3,W3); a7 = csub(P3,W3);
}

__device__ __forceinline__ void fwd_one(float2* __restrict__ S,
    int i0,int i1,int i2,int i3,int i4,int i5,int i6,int i7,
    float2 w1,float2 w2,float2 w3,float2 w4,float2 w5,float2 w6,float2 w7) {
    float2 a0=S[i0],a1=S[i1],a2=S[i2],a3=S[i3],a4=S[i4],a5=S[i5],a6=S[i6],a7=S[i7];
    dft8_fwd(a0,a1,a2,a3,a4,a5,a6,a7);
    S[i0]=a0;           S[i1]=cmul(a1,w1); S[i2]=cmul(a2,w2); S[i3]=cmul(a3,w3);
    S[i4]=cmul(a4,w4);  S[i5]=cmul(a5,w5); S[i6]=cmul(a6,w6); S[i7]=cmul(a7,w7);
}

__device__ __forceinline__ void inv_one(float2* __restrict__ S,
    int i0,int i1,int i2,int i3,int i4,int i5,int i6,int i7,
    float2 w1,float2 w2,float2 w3,float2 w4,float2 w5,float2 w6,float2 w7) {
    float2 a0=S[i0];
    float2 a1=cmul(S[i1],w1), a2=cmul(S[i2],w2), a3=cmul(S[i3],w3), a4=cmul(S[i4],w4),
           a5=cmul(S[i5],w5), a6=cmul(S[i6],w6), a7=cmul(S[i7],w7);
    dft8_inv(a0,a1,a2,a3,a4,a5,a6,a7);
    S[i0]=a0; S[i1]=a1; S[i2]=a2; S[i3]=a3; S[i4]=a4; S[i5]=a5; S[i6]=a6; S[i7]=a7;
}

__device__ __forceinline__ void plain_one_fwd(float2* __restrict__ S, int p) {   // q=1, no twiddles
    const int base = p << 3;
    const int i0=PADL(base),i1=PADL(base+1),i2=PADL(base+2),i3=PADL(base+3),
              i4=PADL(base+4),i5=PADL(base+5),i6=PADL(base+6),i7=PADL(base+7);
    float2 a0=S[i0],a1=S[i1],a2=S[i2],a3=S[i3],a4=S[i4],a5=S[i5],a6=S[i6],a7=S[i7];
    dft8_fwd(a0,a1,a2,a3,a4,a5,a6,a7);
    S[i0]=a0; S[i1]=a1; S[i2]=a2; S[i3]=a3; S[i4]=a4; S[i5]=a5; S[i6]=a6; S[i7]=a7;
}

__device__ __forceinline__ void plain_one_inv(float2* __restrict__ S, int p) {
    const int base = p << 3;
    const int i0=PADL(base),i1=PADL(base+1),i2=PADL(base+2),i3=PADL(base+3),
              i4=PADL(base+4),i5=PADL(base+5),i6=PADL(base+6),i7=PADL(base+7);
    float2 a0=S[i0],a1=S[i1],a2=S[i2],a3=S[i3],a4=S[i4],a5=S[i5],a6=S[i6],a7=S[i7];
    dft8_inv(a0,a1,a2,a3,a4,a5,a6,a7);
    S[i0]=a0; S[i1]=a1; S[i2]=a2; S[i3]=a3; S[i4]=a4; S[i5]=a5; S[i6]=a6; S[i7]=a7;
}

#define WCHAIN(w1, w2,w3,w4,w5,w6,w7) \
    float2 w2 = cmul(w1,w1), w3 = cmul(w2,w1), w4 = cmul(w2,w2), \
           w5 = cmul(w4,w1), w6 = cmul(w4,w2), w7 = cmul(w4,w3)

template<int LQ>
__device__ __forceinline__ void fwd_pair(float2* __restrict__ Sa, float2* __restrict__ Sb, int p) {
    const int q = 1 << LQ;
    const int m = p & (q - 1);
    const int B = ((p >> LQ) << (LQ + 3)) + m;
    const int i0=PADL(B),i1=PADL(B+q),i2=PADL(B+2*q),i3=PADL(B+3*q),
              i4=PADL(B+4*q),i5=PADL(B+5*q),i6=PADL(B+6*q),i7=PADL(B+7*q);
    float sn, cs;
    __sincosf(-TWO_PI * (float)m / (float)(q << 3), &sn, &cs);
    float2 w1 = make_float2(cs, sn);
    WCHAIN(w1, w2,w3,w4,w5,w6,w7);
    fwd_one(Sa,i0,i1,i2,i3,i4,i5,i6,i7,w1,w2,w3,w4,w5,w6,w7);
    fwd_one(Sb,i0,i1,i2,i3,i4,i5,i6,i7,w1,w2,w3,w4,w5,w6,w7);
}

template<int LQ>
__device__ __forceinline__ void inv_pair(float2* __restrict__ Sa, float2* __restrict__ Sb, int p) {
    const int q = 1 << LQ;
    const int m = p & (q - 1);
    const int B = ((p >> LQ) << (LQ + 3)) + m;
    const int i0=PADL(B),i1=PADL(B+q),i2=PADL(B+2*q),i3=PADL(B+3*q),
              i4=PADL(B+4*q),i5=PADL(B+5*q),i6=PADL(B+6*q),i7=PADL(B+7*q);
    float sn, cs;
    __sincosf(TWO_PI * (float)m / (float)(q << 3), &sn, &cs);
    float2 w1 = make_float2(cs, sn);
    WCHAIN(w1, w2,w3,w4,w5,w6,w7);
    inv_one(Sa,i0,i1,i2,i3,i4,i5,i6,i7,w1,w2,w3,w4,w5,w6,w7);
    inv_one(Sb,i0,i1,i2,i3,i4,i5,i6,i7,w1,w2,w3,w4,w5,w6,w7);
}

template<int LQ>
__device__ __forceinline__ void fwd_single(float2* __restrict__ S, int p) {
    const int q = 1 << LQ;
    const int m = p & (q - 1);
    const int B = ((p >> LQ) << (LQ + 3)) + m;
    const int i0=PADL(B),i1=PADL(B+q),i2=PADL(B+2*q),i3=PADL(B+3*q),
              i4=PADL(B+4*q),i5=PADL(B+5*q),i6=PADL(B+6*q),i7=PADL(B+7*q);
    float sn, cs;
    __sincosf(-TWO_PI * (float)m / (float)(q << 3), &sn, &cs);
    float2 w1 = make_float2(cs, sn);
    WCHAIN(w1, w2,w3,w4,w5,w6,w7);
    fwd_one(S,i0,i1,i2,i3,i4,i5,i6,i7,w1,w2,w3,w4,w5,w6,w7);
}

// Q' = Xd*Td + i*Xe*Te  (Td,Te pre-scaled by 0.5/8192 in tsep)
__device__ __forceinline__ float2 qmul(float2 a, float2 A, float4 t) {
    float2 Xd = make_float2((a.x + A.x) * 0.5f, (a.y - A.y) * 0.5f);
    float2 Xe = make_float2((a.y + A.y) * 0.5f, (A.x - a.x) * 0.5f);
    float2 A0 = cmul(Xd, make_float2(t.x, t.y));
    float2 B0 = cmul(Xe, make_float2(t.z, t.w));
    return make_float2(A0.x - B0.y, A0.y + B0.x);
}

// sep on both halves of one pair; one internal barrier
__device__ __forceinline__ void sep_both(float2* __restrict__ Se, float2* __restrict__ So,
                                         const float4* __restrict__ tbE,
                                         const float4* __restrict__ tbO, int p) {
    float2 We[8], Wo[8];
    #pragma unroll
    for (int it = 0; it < 8; ++it) {
        int u = p + (it << 9);
        int K = rev8_12(u);
        int vE = rev8_12((4096 - K) & 4095);       // even half: partner m' = (4096-m)%4096
        int vO = rev8_12(4095 - K);                // odd  half: partner m' = 4095-m
        float2 ae = Se[PADL(u)], Ae = Se[PADL(vE)];
        We[it] = qmul(ae, Ae, tbE[u]);
        float2 ao = So[PADL(u)], Ao = So[PADL(vO)];
        Wo[it] = qmul(ao, Ao, tbO[u]);
    }
    __syncthreads();
    #pragma unroll
    for (int it = 0; it < 8; ++it) {
        int u = p + (it << 9);
        Se[PADL(u)] = We[it];
        So[PADL(u)] = Wo[it];
    }
}

// ---------------- T precompute: 256 blocks x 1024 thr ----------------
__global__ __launch_bounds__(1024, 2) void tsep_k(
    const float* __restrict__ T, float4* __restrict__ Tsep)
{
    extern __shared__ float2 L[];
    float2* Te = L;
    float2* To = L + BUF_ELEMS;
    const int tid = threadIdx.x;

    int h = blockIdx.x;                        // [0,256)
    const int c = ((h & 7) << 5) | (h >> 3);   // 32 consecutive pairs per XCD
    const float* tp = T + (c << 1);

    // fold + modulate: Te[r] = t[r]+t[r+4096]; To[r] = (t[r]-t[r+4096])*e^{-2pi i r/8192}
    {
        float sn, cs;
        __sincosf(-TWO_PI * (float)tid / 8192.0f, &sn, &cs);
        float2 m = make_float2(cs, sn);
        const float2 CF4 = make_float2(RSQRT2, -RSQRT2);   // e^{-i pi/4} per 1024-step
        #pragma unroll
        for (int j = 0; j < 4; ++j) {
            int r = tid + (j << 10);
            float2 va = *(const float2*)(tp + (size_t)r * 512);
            float2 vb = *(const float2*)(tp + (size_t)(r + 4096) * 512);
            Te[PADL(r)] = cadd(va, vb);
            To[PADL(r)] = cmul(csub(va, vb), m);
            m = cmul(m, CF4);
        }
    }
    __syncthreads();                                           // B1

    const int p = tid & 511;
    float2* Sb = (tid >> 9) ? To : Te;
    fwd_single<9>(Sb, p);
    __syncthreads();                                           // B2
    fwd_single<6>(Sb, p);  WFENCE();
    fwd_single<3>(Sb, p);  WFENCE();
    plain_one_fwd(Sb, p);
    __syncthreads();                                           // B3

    const float sc = 0.5f / 8192.0f;
    const int parity = tid >> 9;
    float4* tb = Tsep + (size_t)c * 8192 + (parity << 12);
    #pragma unroll
    for (int it = 0; it < 8; ++it) {
        int u = p + (it << 9);
        int K = rev8_12(u);
        int v = parity ? rev8_12(4095 - K) : rev8_12((4096 - K) & 4095);
        float2 Zk = Sb[PADL(u)], Zn = Sb[PADL(v)];
        tb[u] = make_float4((Zk.x + Zn.x) * sc, (Zk.y - Zn.y) * sc,
                            (Zk.y + Zn.y) * sc, (Zn.x - Zk.x) * sc);
    }
}

// ---------------- main conv: 512 blocks x 1024 thr ----------------
__global__ __launch_bounds__(1024, 2) void fftconv10(
    const float* __restrict__ X, const float4* __restrict__ Tsep,
    float* __restrict__ O)
{
    extern __shared__ float2 L[];
    const int tid = threadIdx.x;

    // R5 swizzle: 4 consecutive-g blocks per XCD
    int h = blockIdx.x;                        // [0,512)
    int xcd = h & 7, sl = h >> 3;
    int lbid = ((sl >> 2) << 5) | (xcd << 2) | (sl & 3);
    const int b = lbid >> 7;
    const int g = lbid & 127;                  // 2 pairs = 4 channels
    const float* xp = X + (size_t)b * 4096 * 512 + (g << 2);

    float2* Ze0 = L;
    float2* Zo0 = L + BUF_ELEMS;
    float2* Ze1 = L + 2 * BUF_ELEMS;
    float2* Zo1 = L + 3 * BUF_ELEMS;

    // ---- load float4 rows; raw -> Ze, modulated -> Zo ----
    {
        float sn, cs;
        __sincosf(-TWO_PI * (float)tid / 8192.0f, &sn, &cs);
        float2 m = make_float2(cs, sn);
        const float2 CF4 = make_float2(RSQRT2, -RSQRT2);   // e^{-i pi/4}
        #pragma unroll
        for (int j = 0; j < 4; ++j) {
            int r = tid + (j << 10);
            float4 v = *(const float4*)(xp + (size_t)r * 512);
            float2 z0 = make_float2(v.x, v.y);
            float2 z1 = make_float2(v.z, v.w);
            Ze0[PADL(r)] = z0;
            Zo0[PADL(r)] = cmul(z0, m);
            Ze1[PADL(r)] = z1;
            Zo1[PADL(r)] = cmul(z1, m);
            m = cmul(m, CF4);
        }
    }
    __syncthreads();                                           // B1

    const int p = tid & 511;
    const int bp = tid >> 9;                   // which pair this thread owns
    float2* Sa = L + (size_t)(2 * bp) * BUF_ELEMS;     // Ze of my pair
    float2* Sb = Sa + BUF_ELEMS;                        // Zo of my pair

    fwd_pair<9>(Sa, Sb, p);
    __syncthreads();                                           // B2
    fwd_pair<6>(Sa, Sb, p);  WFENCE();                         // wave-local
    fwd_pair<3>(Sa, Sb, p);  WFENCE();                         // wave-local
    plain_one_fwd(Sa, p);    plain_one_fwd(Sb, p);
    __syncthreads();                                           // B3

    const int cglob = 2 * g + bp;
    const float4* tbE = Tsep + (size_t)cglob * 8192;
    sep_both(Sa, Sb, tbE, tbE + 4096, p);                      // internal B4
    __syncthreads();                                           // B5

    plain_one_inv(Sa, p);    plain_one_inv(Sb, p);  WFENCE();  // wave-local
    inv_pair<3>(Sa, Sb, p);  WFENCE();                         // wave-local
    inv_pair<6>(Sa, Sb, p);
    __syncthreads();                                           // B6

    // ---- inverse final (q=512) + even/odd recombine + store ----
    {
        float sn, cs;
        __sincosf(TWO_PI * (float)p / 4096.0f, &sn, &cs);
        float2 w1 = make_float2(cs, sn);
        WCHAIN(w1, w2,w3,w4,w5,w6,w7);
        float2 e0 = Sa[PADL(p)];
        float2 e1 = cmul(Sa[PADL(p +  512)], w1);
        float2 e2 = cmul(Sa[PADL(p + 1024)], w2);
        float2 e3 = cmul(Sa[PADL(p + 1536)], w3);
        float2 e4 = cmul(Sa[PADL(p + 2048)], w4);
        float2 e5 = cmul(Sa[PADL(p + 2560)], w5);
        float2 e6 = cmul(Sa[PADL(p + 3072)], w6);
        float2 e7 = cmul(Sa[PADL(p + 3584)], w7);
        dft8_inv(e0,e1,e2,e3,e4,e5,e6,e7);
        float2 o0 = Sb[PADL(p)];
        float2 o1 = cmul(Sb[PADL(p +  512)], w1);
        float2 o2 = cmul(Sb[PADL(p + 1024)], w2);
        float2 o3 = cmul(Sb[PADL(p + 1536)], w3);
        float2 o4 = cmul(Sb[PADL(p + 2048)], w4);
        float2 o5 = cmul(Sb[PADL(p + 2560)], w5);
        float2 o6 = cmul(Sb[PADL(p + 3072)], w6);
        float2 o7 = cmul(Sb[PADL(p + 3584)], w7);
        dft8_inv(o0,o1,o2,o3,o4,o5,o6,o7);

        __sincosf(TWO_PI * (float)p / 8192.0f, &sn, &cs);
        float2 cmb = make_float2(cs, sn);                      // e^{+2pi i p/8192}
        const float2 CI8 = make_float2(0.92387953251128675613f,
                                       0.38268343236508977173f); // e^{+i pi/8}
        float* op = O + (size_t)b * 4096 * 512 + (g << 2) + (bp << 1);
        *(float2*)(op + (size_t)(p         ) * 512) = cadd(e0, cmul(o0, cmb)); cmb = cmul(cmb, CI8);
        *(float2*)(op + (size_t)(p +  512) * 512) = cadd(e1, cmul(o1, cmb)); cmb = cmul(cmb, CI8);
        *(float2*)(op + (size_t)(p + 1024) * 512) = cadd(e2, cmul(o2, cmb)); cmb = cmul(cmb, CI8);
        *(float2*)(op + (size_t)(p + 1536) * 512) = cadd(e3, cmul(o3, cmb)); cmb = cmul(cmb, CI8);
        *(float2*)(op + (size_t)(p + 2048) * 512) = cadd(e4, cmul(o4, cmb)); cmb = cmul(cmb, CI8);
        *(float2*)(op + (size_t)(p + 2560) * 512) = cadd(e5, cmul(o5, cmb)); cmb = cmul(cmb, CI8);
        *(float2*)(op + (size_t)(p + 3072) * 512) = cadd(e6, cmul(o6, cmb)); cmb = cmul(cmb, CI8);
        *(float2*)(op + (size_t)(p + 3584) * 512) = cadd(e7, cmul(o7, cmb));
    }
}

extern "C" void kernel_launch(void* const* d_in, const int* in_sizes, int n_in,
                              void* d_out, int out_size, void* d_ws, size_t ws_size,
                              hipStream_t stream)
{
    const float* x = (const float*)d_in[0];   // (4, 4096, 512)
    const float* t = (const float*)d_in[1];   // (8192, 512)
    float* out = (float*)d_out;               // (4, 4096, 512)
    float4* tsep = (float4*)d_ws;             // 256 pairs * 8192 * 16 B = 32 MB

    const int lds_t = (int)(2 * BUF_ELEMS * sizeof(float2));  // 69632
    const int lds_c = (int)(4 * BUF_ELEMS * sizeof(float2));  // 139264
    (void)hipFuncSetAttribute((const void*)tsep_k,
                              hipFuncAttributeMaxDynamicSharedMemorySize, lds_t);
    (void)hipFuncSetAttribute((const void*)fftconv10,
                              hipFuncAttributeMaxDynamicSharedMemorySize, lds_c);

    tsep_k<<<256, 1024, lds_t, stream>>>(t, tsep);
    fftconv10<<<512, 1024, lds_c, stream>>>(x, tsep, out);
}